// Round 1
// baseline (1920.762 us; speedup 1.0000x reference)
//
#include <hip/hip_runtime.h>

// CRF forward on MI355X — R3: matvec on the MFMA pipe.
//
// R2 was LDS-return-bandwidth bound: every thread re-read all of V each step
// (128 KB/step of lane data; LDS return path ~128 B/cy/CU, no broadcast dedup
// on return) -> ~1024 cyc/step floor, measured 1900. Any VALU split-K keeps
// that traffic invariant. Fix: keep E = exp(trans) resident in registers as
// MFMA A-fragments; per step only V moves, loaded into COLUMN 0 of the
// B-fragment (only lanes with lane&15==0 carry col 0; all other lanes' B regs
// stay zero so D cols 1..15 are exactly 0 and ignored). LDS/step: 128KB -> 4KB.
//
// Normalization is DEFERRED one step: scale step t by g = 2^-5 / Sigma_{t-1},
// where Sigma_{t-1} comes from 16 per-lane partials written last step. Any g
// is exact as long as it's logged: Lam accumulates log2(Sigma). This deletes
// the "ones-dot" half of R2's FLOPs and needs no same-step reduction.
//
// Barrier is raw lgkmcnt(0)+s_barrier (no vmcnt drain) so the 1-step-ahead
// y prefetch survives across it. 512 thr = 8 waves (32 rows each), 2/SIMD.

typedef _Float16 f16x8 __attribute__((ext_vector_type(8)));
typedef _Float16 f16x4 __attribute__((ext_vector_type(4)));
typedef float    f32x4 __attribute__((ext_vector_type(4)));

#define TT 2048
#define KK 256
#define NTH 512
#define NW (NTH / 64)
#define SOS_IDX 2
#define CSCALE 0.03125f   // 2^-5 target sum; -log2 = 5 folded into epilogue

__global__ __launch_bounds__(NTH, 2)
void crf_fwd_kernel(const float* __restrict__ y, const float* __restrict__ mask,
                    const float* __restrict__ trans, float* __restrict__ out)
{
    const int tid = threadIdx.x;
    const int b   = blockIdx.x;
    const int w   = tid >> 6;       // wave 0..7, owns output rows [32w, 32w+32)
    const int l   = tid & 63;
    const int m16 = l & 15;         // A-fragment row within 16-tile
    const int s   = l >> 4;         // k-subgroup 0..3
    const bool act = (m16 == 0);    // lanes carrying B col 0 / D col 0

    __shared__ __align__(16) _Float16 Wbuf[2][KK];   // prob vector, double buffered
    __shared__ __align__(16) float    sred[2][16];   // per-step sum partials
    __shared__ float sl[NW];

    // ---- A fragments: af[rt][kt] = E rows 32w+16rt+(l&15), cols 32kt+8s..+8
    f16x8 af[2][8];
    #pragma unroll
    for (int rt = 0; rt < 2; ++rt) {
        const float* tr = trans + (size_t)(32 * w + 16 * rt + m16) * KK + 8 * s;
        #pragma unroll
        for (int kt = 0; kt < 8; ++kt) {
            float4 v0 = *(const float4*)(tr + 32 * kt);
            float4 v1 = *(const float4*)(tr + 32 * kt + 4);
            f16x8 a;
            a[0] = (_Float16)__expf(v0.x); a[1] = (_Float16)__expf(v0.y);
            a[2] = (_Float16)__expf(v0.z); a[3] = (_Float16)__expf(v0.w);
            a[4] = (_Float16)__expf(v1.x); a[5] = (_Float16)__expf(v1.y);
            a[6] = (_Float16)__expf(v1.z); a[7] = (_Float16)__expf(v1.w);
            af[rt][kt] = a;
        }
    }

    // ---- L = sum(mask[b,:])
    {
        float lsum = 0.f;
        const float* mrow = mask + (size_t)b * TT;
        #pragma unroll
        for (int i = 0; i < TT / NTH; ++i) lsum += mrow[tid + i * NTH];
        #pragma unroll
        for (int off = 32; off >= 1; off >>= 1) lsum += __shfl_xor(lsum, off, 64);
        if (l == 0) sl[w] = lsum;
    }

    if (tid < KK) Wbuf[0][tid] = (_Float16)((tid == SOS_IDX) ? 1.f : 0.f);
    if (tid < 16) sred[0][tid] = 0.0625f;   // 16 * 1/16 -> Sigma_0 = 1 (log2 = 0)
    __syncthreads();

    float Ls = 0.f;
    #pragma unroll
    for (int i = 0; i < NW; ++i) Ls += sl[i];
    const int L = (int)(Ls + 0.5f);

    // y rows this active lane owns: 32w+4s+{0..3} and +16
    const float* yb = y + (size_t)b * TT * KK + 32 * w + 4 * s;
    float Lam = 0.f;

    f16x8 bf[8];
    {
        const f16x8 fz = {(_Float16)0.f, (_Float16)0.f, (_Float16)0.f, (_Float16)0.f,
                          (_Float16)0.f, (_Float16)0.f, (_Float16)0.f, (_Float16)0.f};
        #pragma unroll
        for (int i = 0; i < 8; ++i) bf[i] = fz;   // inactive lanes: B cols 1..15 == 0 forever
    }

    float4 yA0, yA1, yB0, yB1;
    if (act) { yA0 = *(const float4*)yb; yA1 = *(const float4*)(yb + 16); }

    auto STEP = [&](int t, const float4 yc0, const float4 yc1, float4& yn0, float4& yn1) {
        const int par = t & 1;
        float g = 0.f;
        if (act) {
            // prefetch next step's y (clamped; covered by this step's compute)
            const int tn = (t + 1 < L) ? (t + 1) : (L - 1);
            yn0 = *(const float4*)(yb + (size_t)tn * KK);
            yn1 = *(const float4*)(yb + (size_t)tn * KK + 16);
            // B col 0: W[32kt + 8s .. +8]
            const f16x8* Wv = (const f16x8*)Wbuf[par];
            #pragma unroll
            for (int kt = 0; kt < 8; ++kt) bf[kt] = Wv[4 * kt + s];
            // deferred normalizer from last step's partials
            const float4* sp = (const float4*)sred[par];
            float4 p0 = sp[0], p1 = sp[1], p2 = sp[2], p3 = sp[3];
            float Sg = ((p0.x + p0.y) + (p0.z + p0.w)) + ((p1.x + p1.y) + (p1.z + p1.w))
                     + ((p2.x + p2.y) + (p2.z + p2.w)) + ((p3.x + p3.y) + (p3.z + p3.w));
            Lam += __log2f(Sg);
            g = CSCALE * __builtin_amdgcn_rcpf(Sg);
        }
        // whole-wave MFMA (must NOT be masked): q = E_rows * W, col 0 only
        f32x4 c0a = {0.f, 0.f, 0.f, 0.f}, c0b = c0a, c1a = c0a, c1b = c0a;
        #pragma unroll
        for (int kt = 0; kt < 4; ++kt) {
            c0a = __builtin_amdgcn_mfma_f32_16x16x32_f16(af[0][kt],     bf[kt],     c0a, 0, 0, 0);
            c1a = __builtin_amdgcn_mfma_f32_16x16x32_f16(af[1][kt],     bf[kt],     c1a, 0, 0, 0);
            c0b = __builtin_amdgcn_mfma_f32_16x16x32_f16(af[0][kt + 4], bf[kt + 4], c0b, 0, 0, 0);
            c1b = __builtin_amdgcn_mfma_f32_16x16x32_f16(af[1][kt + 4], bf[kt + 4], c1b, 0, 0, 0);
        }
        if (act) {
            // D col 0, rows 4s+reg (+16 for rt=1): matches yc0/yc1 rows exactly
            const f32x4 c0 = c0a + c0b, c1 = c1a + c1b;
            float w0 = __expf(yc0.x) * c0[0] * g;
            float w1 = __expf(yc0.y) * c0[1] * g;
            float w2 = __expf(yc0.z) * c0[2] * g;
            float w3 = __expf(yc0.w) * c0[3] * g;
            float w4 = __expf(yc1.x) * c1[0] * g;
            float w5 = __expf(yc1.y) * c1[1] * g;
            float w6 = __expf(yc1.z) * c1[2] * g;
            float w7 = __expf(yc1.w) * c1[3] * g;
            f16x4 h0 = {(_Float16)w0, (_Float16)w1, (_Float16)w2, (_Float16)w3};
            f16x4 h1 = {(_Float16)w4, (_Float16)w5, (_Float16)w6, (_Float16)w7};
            *(f16x4*)&Wbuf[par ^ 1][32 * w + 4 * s]      = h0;
            *(f16x4*)&Wbuf[par ^ 1][32 * w + 16 + 4 * s] = h1;
            float ps = ((w0 + w1) + (w2 + w3)) + ((w4 + w5) + (w6 + w7));
            ps += __shfl_xor(ps, 16, 64);              // s0+s1 at lanes 0/16, s2+s3 at 32/48
            if ((l & 31) == 0) sred[par ^ 1][2 * w + (l >> 5)] = ps;
        }
        // LDS-only barrier: keep y prefetch (vmcnt) in flight across it
        asm volatile("s_waitcnt lgkmcnt(0)" ::: "memory");
        __builtin_amdgcn_s_barrier();
    };

    for (int t = 0; t < L; t += 2) {
        STEP(t, yA0, yA1, yB0, yB1);
        if (t + 1 < L) STEP(t + 1, yB0, yB1, yA0, yA1);
    }

    if (tid == 0) {
        const float* sp = sred[L & 1];
        float Sf = 0.f;
        #pragma unroll
        for (int i = 0; i < 16; ++i) Sf += sp[i];
        // logZ = ln2 * ( sum_{s=0..L-1} log2 Sigma_s + log2 Sigma_L + 5L )
        out[b] = 0.69314718056f * (Lam + __log2f(Sf) + 5.0f * (float)L);
    }
}

extern "C" void kernel_launch(void* const* d_in, const int* in_sizes, int n_in,
                              void* d_out, int out_size, void* d_ws, size_t ws_size,
                              hipStream_t stream) {
    const float* y     = (const float*)d_in[0];   // (B, T, K) fp32
    const float* mask  = (const float*)d_in[1];   // (B, T)    fp32
    const float* trans = (const float*)d_in[2];   // (K, K)    fp32
    float* out = (float*)d_out;                   // (B,)      fp32
    const int B = in_sizes[1] / TT;
    crf_fwd_kernel<<<B, NTH, 0, stream>>>(y, mask, trans, out);
}

// Round 3
// 1481.843 us; speedup vs baseline: 1.2962x; 1.2962x over previous
//
#include <hip/hip_runtime.h>

// CRF forward on MI355X — R4b: 16 batches per block, dense-column MFMA.
// (Resubmission of R4 — previous bench died on container acquire, no data.)
//
// R3 post-mortem: mfma_16x16x32_f16 costs ~20.6 cyc/SIMD (1955 TF ubench), so the
// 128 MFMAs/CU/step of a 256x256 matvec are ~660 cyc/SIMD *regardless of column
// fill*. R3 used 1 of 16 D-columns -> paid full matmul price for matvec work.
// R4 fills all 16 B/D columns with 16 independent batch chains: same MFMA cost,
// 16x the work retired. grid = B/16 = 4 blocks, 8 waves each.
//
// Per wave: 2 row-tiles (rows 32w..32w+31), A = exp(trans) static in regs,
// B = V[k][batch] from LDS (stored [batch][k] fp16, XOR-swizzled: byte ^= (c&7)<<4
// -> b128 reads land 8 words/bank = wave64 minimum, conflict-free). Per-column
// deferred normalizer g_c = 2^-5/Sigma_c (previous step's sum, 8 wave-partials in
// LDS); exact via Lam += log2(Sigma). Mask: per-column freeze — W kept in f32
// regs, frozen cols re-select old values (bit-exact). y prefetched 2 steps ahead
// in regs; barrier is lgkmcnt-only so y loads stay in flight across it.

typedef _Float16 f16x8 __attribute__((ext_vector_type(8)));
typedef _Float16 f16x4 __attribute__((ext_vector_type(4)));
typedef float    f32x4 __attribute__((ext_vector_type(4)));

#define TT 2048
#define KK 256
#define NB 16
#define NTH 512
#define SOS_IDX 2

#define MFMA(A, B, C) __builtin_amdgcn_mfma_f32_16x16x32_f16((A), (B), (C), 0, 0, 0)

__global__ __launch_bounds__(NTH, 2)
void crf_fwd_kernel(const float* __restrict__ y, const float* __restrict__ mask,
                    const float* __restrict__ trans, float* __restrict__ out)
{
    const int tid = threadIdx.x;
    const int w = tid >> 6, l = tid & 63;
    const int c = l & 15;            // column = batch-in-block (also A-row-in-tile)
    const int s = l >> 4;            // k-subgroup 0..3
    const int sw = (c & 7) << 4;     // LDS XOR swizzle (bits 4..6 of byte offset)
    const int bb = blockIdx.x * NB;

    __shared__ __align__(16) char  Vlds[2][NB * 512];   // [par][c][k] fp16, swizzled
    __shared__ __align__(16) float sred[2][NB][12];     // [par][c][wave] sum partials
    __shared__ float Lcs[NB];

    // ---- A fragments: af{0,1}[kt] = exp(trans)[32w + 16*rt + c][32kt + 8s + j]
    f16x8 af0[8], af1[8];
    {
        const float* t0 = trans + (size_t)(32 * w + c) * KK + 8 * s;
        const float* t1 = t0 + 16 * KK;
        #pragma unroll
        for (int kt = 0; kt < 8; ++kt) {
            float4 a0 = *(const float4*)(t0 + 32 * kt);
            float4 a1 = *(const float4*)(t0 + 32 * kt + 4);
            float4 b0 = *(const float4*)(t1 + 32 * kt);
            float4 b1 = *(const float4*)(t1 + 32 * kt + 4);
            f16x8 A, Bv;
            A[0] = (_Float16)__expf(a0.x); A[1] = (_Float16)__expf(a0.y);
            A[2] = (_Float16)__expf(a0.z); A[3] = (_Float16)__expf(a0.w);
            A[4] = (_Float16)__expf(a1.x); A[5] = (_Float16)__expf(a1.y);
            A[6] = (_Float16)__expf(a1.z); A[7] = (_Float16)__expf(a1.w);
            Bv[0] = (_Float16)__expf(b0.x); Bv[1] = (_Float16)__expf(b0.y);
            Bv[2] = (_Float16)__expf(b0.z); Bv[3] = (_Float16)__expf(b0.w);
            Bv[4] = (_Float16)__expf(b1.x); Bv[5] = (_Float16)__expf(b1.y);
            Bv[6] = (_Float16)__expf(b1.z); Bv[7] = (_Float16)__expf(b1.w);
            af0[kt] = A; af1[kt] = Bv;
        }
    }

    // ---- per-column lengths: 32 threads per batch row
    {
        const int cq = tid >> 5, q = tid & 31;
        const float* mrow = mask + (size_t)(bb + cq) * TT;
        float ls = 0.f;
        #pragma unroll
        for (int i = 0; i < TT / 32; ++i) ls += mrow[q + 32 * i];
        #pragma unroll
        for (int off = 16; off >= 1; off >>= 1) ls += __shfl_xor(ls, off, 64);
        if (q == 0) Lcs[cq] = ls;
    }

    // ---- init W (f32 regs, rows 32w+4s+{0..3} and +16, col c) = one-hot(SOS)
    const int r0 = 32 * w + 4 * s;
    float W0 = (r0 + 0 == SOS_IDX) ? 1.f : 0.f;
    float W1 = (r0 + 1 == SOS_IDX) ? 1.f : 0.f;
    float W2 = (r0 + 2 == SOS_IDX) ? 1.f : 0.f;
    float W3 = (r0 + 3 == SOS_IDX) ? 1.f : 0.f;
    float W4 = (r0 + 16 == SOS_IDX) ? 1.f : 0.f;
    float W5 = (r0 + 17 == SOS_IDX) ? 1.f : 0.f;
    float W6 = (r0 + 18 == SOS_IDX) ? 1.f : 0.f;
    float W7 = (r0 + 19 == SOS_IDX) ? 1.f : 0.f;
    {
        char* wb = Vlds[0] + (c << 9);
        f16x4 h0 = {(_Float16)W0, (_Float16)W1, (_Float16)W2, (_Float16)W3};
        f16x4 h1 = {(_Float16)W4, (_Float16)W5, (_Float16)W6, (_Float16)W7};
        *(f16x4*)(wb + ((64 * w + 8 * s) ^ sw))      = h0;
        *(f16x4*)(wb + ((64 * w + 32 + 8 * s) ^ sw)) = h1;
        float ps = ((W0 + W1) + (W2 + W3)) + ((W4 + W5) + (W6 + W7));
        ps += __shfl_xor(ps, 16, 64);
        ps += __shfl_xor(ps, 32, 64);
        if (s == 0) sred[0][c][w] = ps;   // Sigma_0 = 1 per column
    }
    __syncthreads();

    float Tm = 0.f;
    #pragma unroll
    for (int i = 0; i < NB; ++i) Tm = fmaxf(Tm, Lcs[i]);
    const int Tmax = (int)(Tm + 0.5f);
    const int Lci  = (int)(Lcs[c] + 0.5f);

    // ---- y prefetch (2 ahead): lane owns (batch bb+c, rows r0..r0+3 and +16)
    const float* yb = y + (size_t)(bb + c) * (TT * KK) + 32 * w + 4 * s;
    float4 yA0 = *(const float4*)(yb);
    float4 yA1 = *(const float4*)(yb + 16);
    const int t1i = (Tmax > 1) ? 1 : 0;
    float4 yB0 = *(const float4*)(yb + (size_t)t1i * KK);
    float4 yB1 = *(const float4*)(yb + (size_t)t1i * KK + 16);
    float Lam = 0.f;

#define STEP(PAR, Y0, Y1, TS)                                                    \
  {                                                                              \
    const int t_ = (TS);                                                         \
    const char* vb = Vlds[PAR] + (c << 9);                                       \
    f16x8 b0 = *(const f16x8*)(vb + ((0   + (s << 4)) ^ sw));                    \
    f16x8 b1 = *(const f16x8*)(vb + ((64  + (s << 4)) ^ sw));                    \
    f16x8 b2 = *(const f16x8*)(vb + ((128 + (s << 4)) ^ sw));                    \
    f16x8 b3 = *(const f16x8*)(vb + ((192 + (s << 4)) ^ sw));                    \
    f16x8 b4 = *(const f16x8*)(vb + ((256 + (s << 4)) ^ sw));                    \
    f16x8 b5 = *(const f16x8*)(vb + ((320 + (s << 4)) ^ sw));                    \
    f16x8 b6 = *(const f16x8*)(vb + ((384 + (s << 4)) ^ sw));                    \
    f16x8 b7 = *(const f16x8*)(vb + ((448 + (s << 4)) ^ sw));                    \
    float4 sp0 = *(const float4*)&sred[PAR][c][0];                               \
    float4 sp1 = *(const float4*)&sred[PAR][c][4];                               \
    float Sg = ((sp0.x + sp0.y) + (sp0.z + sp0.w)) +                             \
               ((sp1.x + sp1.y) + (sp1.z + sp1.w));                              \
    float g  = 0.03125f * __builtin_amdgcn_rcpf(Sg);                             \
    float lg = __log2f(Sg);                                                      \
    f32x4 zz = {0.f, 0.f, 0.f, 0.f};                                             \
    f32x4 c0a = zz, c0b = zz, c1a = zz, c1b = zz;                                \
    c0a = MFMA(af0[0], b0, c0a); c1a = MFMA(af1[0], b0, c1a);                    \
    c0b = MFMA(af0[4], b4, c0b); c1b = MFMA(af1[4], b4, c1b);                    \
    c0a = MFMA(af0[1], b1, c0a); c1a = MFMA(af1[1], b1, c1a);                    \
    c0b = MFMA(af0[5], b5, c0b); c1b = MFMA(af1[5], b5, c1b);                    \
    c0a = MFMA(af0[2], b2, c0a); c1a = MFMA(af1[2], b2, c1a);                    \
    c0b = MFMA(af0[6], b6, c0b); c1b = MFMA(af1[6], b6, c1b);                    \
    c0a = MFMA(af0[3], b3, c0a); c1a = MFMA(af1[3], b3, c1a);                    \
    c0b = MFMA(af0[7], b7, c0b); c1b = MFMA(af1[7], b7, c1b);                    \
    const bool on = (t_ < Lci);                                                  \
    f32x4 q0 = c0a + c0b, q1 = c1a + c1b;                                        \
    float n0 = on ? __expf(Y0.x) * q0[0] * g : W0;                               \
    float n1 = on ? __expf(Y0.y) * q0[1] * g : W1;                               \
    float n2 = on ? __expf(Y0.z) * q0[2] * g : W2;                               \
    float n3 = on ? __expf(Y0.w) * q0[3] * g : W3;                               \
    float n4 = on ? __expf(Y1.x) * q1[0] * g : W4;                               \
    float n5 = on ? __expf(Y1.y) * q1[1] * g : W5;                               \
    float n6 = on ? __expf(Y1.z) * q1[2] * g : W6;                               \
    float n7 = on ? __expf(Y1.w) * q1[3] * g : W7;                               \
    W0 = n0; W1 = n1; W2 = n2; W3 = n3; W4 = n4; W5 = n5; W6 = n6; W7 = n7;      \
    Lam += on ? lg : 0.f;                                                        \
    char* wb = Vlds[(PAR) ^ 1] + (c << 9);                                       \
    f16x4 h0 = {(_Float16)n0, (_Float16)n1, (_Float16)n2, (_Float16)n3};         \
    f16x4 h1 = {(_Float16)n4, (_Float16)n5, (_Float16)n6, (_Float16)n7};         \
    *(f16x4*)(wb + ((64 * w + 8 * s) ^ sw))      = h0;                           \
    *(f16x4*)(wb + ((64 * w + 32 + 8 * s) ^ sw)) = h1;                           \
    float ps = ((n0 + n1) + (n2 + n3)) + ((n4 + n5) + (n6 + n7));                \
    ps += __shfl_xor(ps, 16, 64);                                                \
    ps += __shfl_xor(ps, 32, 64);                                                \
    if (s == 0) sred[(PAR) ^ 1][c][w] = ps;                                      \
    { int tn = t_ + 2; if (tn > Tmax - 1) tn = Tmax - 1;                         \
      Y0 = *(const float4*)(yb + (size_t)tn * KK);                               \
      Y1 = *(const float4*)(yb + (size_t)tn * KK + 16); }                        \
    asm volatile("s_waitcnt lgkmcnt(0)" ::: "memory");                           \
    __builtin_amdgcn_s_barrier();                                                \
    __builtin_amdgcn_sched_barrier(0);                                           \
  }

    int t = 0;
    for (; t + 1 < Tmax; t += 2) {
        STEP(0, yA0, yA1, t);
        STEP(1, yB0, yB1, t + 1);
    }
    if (t < Tmax) STEP(0, yA0, yA1, t);

#undef STEP

    if (tid < NB) {   // wave 0, lane tid: c == tid, has col-tid's Lam/Lci
        const int fin = Tmax & 1;
        float Sf = 0.f;
        #pragma unroll
        for (int i = 0; i < 8; ++i) Sf += sred[fin][tid][i];
        out[bb + tid] = 0.69314718056f * (Lam + __log2f(Sf) + 5.0f * (float)Lci);
    }
}

extern "C" void kernel_launch(void* const* d_in, const int* in_sizes, int n_in,
                              void* d_out, int out_size, void* d_ws, size_t ws_size,
                              hipStream_t stream) {
    const float* y     = (const float*)d_in[0];   // (B, T, K) fp32
    const float* mask  = (const float*)d_in[1];   // (B, T)    fp32
    const float* trans = (const float*)d_in[2];   // (K, K)    fp32
    float* out = (float*)d_out;                   // (B,)      fp32
    const int B = in_sizes[1] / TT;
    crf_fwd_kernel<<<B / NB, NTH, 0, stream>>>(y, mask, trans, out);
}